// Round 8
// baseline (2498.164 us; speedup 1.0000x reference)
//
#include <hip/hip_runtime.h>
#include <hip/hip_bf16.h>

#define H 128
#define FOURH 512
#define BATCH 64
#define SEQ 2048
#define TC SEQ
#define NCHUNK 128                 // 2048 / 16 steps per chunk
#define GSTRIDE (BATCH * FOURH)    // floats per t-major slot [64][512]

typedef _Float16 half8 __attribute__((ext_vector_type(8)));
typedef float f32x4 __attribute__((ext_vector_type(4)));

// ---- prep: transpose Wih0 -> [K][512], fp16 Wih1, sum biases, zero flags ----
__global__ void prep_kernel(const float* __restrict__ Wih0,
                            const float* __restrict__ bih0, const float* __restrict__ bhh0,
                            const float* __restrict__ bih1, const float* __restrict__ bhh1,
                            const float* __restrict__ Wih1,
                            float* __restrict__ Wt0,
                            float* __restrict__ b0, float* __restrict__ b1,
                            _Float16* __restrict__ wt1h,
                            int* __restrict__ flags) {
    int id = blockIdx.x * 256 + threadIdx.x;
    const int N0 = 256 * 512;
    if (id < N0) {
        int k = id >> 9, n = id & 511;
        Wt0[id] = Wih0[n * 256 + k];
    } else if (id < N0 + 512) {
        int i = id - N0;
        b0[i] = bih0[i] + bhh0[i];
    } else if (id < N0 + 1024) {
        int i = id - (N0 + 512);
        b1[i] = bih1[i] + bhh1[i];
    } else if (id < N0 + 1024 + 65536) {
        int i = id - (N0 + 1024);
        wt1h[i] = (_Float16)Wih1[i];          // same RNE rounding the consumer used
    } else if (id < N0 + 1024 + 65536 + 272) {
        flags[id - (N0 + 1024 + 65536)] = 0;
    }
}

// ---------------- fused persistent kernel ----------------
__device__ __forceinline__ float sigmoid_f(float x) {
    return __builtin_amdgcn_rcpf(1.f + __expf(-x));
}
__device__ __forceinline__ float tanh_f(float x) {
    return 1.f - 2.f * __builtin_amdgcn_rcpf(__expf(2.f * x) + 1.f);
}

// Light barrier: LDS handoff only. Global loads/stores stay in flight across it.
#define LDS_BARRIER()                                                \
    do {                                                             \
        asm volatile("s_waitcnt lgkmcnt(0)" ::: "memory");           \
        __builtin_amdgcn_s_barrier();                                \
        __builtin_amdgcn_sched_barrier(0);                           \
    } while (0)

#define BM 128
#define BN 128
#define BK 32

// PHASE-REUSED gbuf: t-major [2048][64][512] f32. Per-slot lifecycle
//   G0-write -> producer-read -> G1-write (same slot) -> consumer-read
// with each arrow enforced by an acquire/release flag chain:
//   producer waits chunkDone[k] (G0 complete);
//   G1 workers wait prodF>=16(m+1)  -- producer consumed slots < 16(m+1),
//     its 4-deep prefetch register-holds values before prodF advances;
//   consumer waits g1Done[k] (+ initial 96-step lag behind producer).
// Wait DAG: G0 -> nothing, producer -> G0, G1 -> producer, consumer -> G1.
// Acyclic, one writer per (slot,phase) => race- and deadlock-free, replay-
// deterministic. No ring masking anywhere; prefetch overrun clamped to 2047.
//
// Grid: 240 blocks x 512 threads.
//   0-7     producer: layer-0 scan, 16 MFMA/wave/step, reads G0 phase,
//           writes h1p, publishes prodF every 16 steps.
//   8-15    consumer: layer-1 recurrent-only scan, 16 MFMA/wave/step,
//           reads G1 phase, writes out directly.
//   16-175  G0 workers (5 classes x 32): free-running fp32 GEMM
//           x@Wih0^T+b0 into slots t, chunkDone[idx] += 1 (target 32).
//   176-239 G1 workers (2 classes x 32): fp16-MFMA h1@Wih1^T+b1 into the
//           SAME slots, g1Done[m] += 1 (target 32). Bit-exact replay of the
//           R1 consumer's input-MFMA chain (fp32 round-trip is exact).
__global__ __launch_bounds__(512, 2) void lstm_fused_kernel(
    const float* __restrict__ x,      // [64][T][256]
    const float* __restrict__ Wt0,    // [256][512] transposed Wih0
    const float* __restrict__ b0sum,  // [512] summed layer-0 biases
    float* __restrict__ Gbuf,         // [T][64][512] phase-reused gate buffer
    const float* __restrict__ Whh0,   // [512][128]
    const _Float16* __restrict__ wt1h,// [512][128] fp16 Wih1
    const float* __restrict__ Whh1,   // [512][128]
    const float* __restrict__ b1,     // [512] summed layer-1 biases
    _Float16* __restrict__ h1p,       // [T][64][128] fp16 layer-0 hidden
    float* __restrict__ out,          // [64][T][128] fp32 layer-1 hidden
    int* __restrict__ flags)          // [8]prodF [8]pad [128]chunkDone [128]g1Done
{
    const int tid = threadIdx.x;

    int* prodF     = flags;
    int* chunkDone = flags + 16;
    int* g1Done    = flags + 144;

    __shared__ _Float16 hbuf[2][8][136];   // scan recurrent h, fp16, dbuf
    __shared__ float As[BK][BM + 4];       // G0 worker staging
    __shared__ float Bs[BK][BN];

    if (blockIdx.x >= 176) {
        // ================= G1 workers: layer-1 input projection =================
        const int j   = blockIdx.x - 176;   // 0..63
        const int sub = j & 31;
        const int cls = j >> 5;             // 0..1
        const int by  = sub >> 2;           // batch group 0..7
        const int bx  = sub & 3;
        const int n0  = bx * BN;
        const int wv  = tid >> 6;           // wave -> batch within group
        const int l   = tid & 63;
        const int li  = l & 15;
        const int q   = l >> 4;
        const int gb1 = 8 * by + wv;

        float bv1g[8];
#pragma unroll
        for (int ct = 0; ct < 8; ++ct) bv1g[ct] = b1[n0 + ct * 16 + li];

        for (int m = cls; m < NCHUNK; m += 2) {
            if (tid == 0) {
                while (__hip_atomic_load(&prodF[by], __ATOMIC_RELAXED,
                                         __HIP_MEMORY_SCOPE_AGENT) < 16 * (m + 1))
                    __builtin_amdgcn_s_sleep(4);
                (void)__hip_atomic_load(&prodF[by], __ATOMIC_ACQUIRE,
                                        __HIP_MEMORY_SCOPE_AGENT);
            }
            __syncthreads();

            const int t0 = m * 16;
            half8 Af[4];
            const _Float16* ap = h1p + ((size_t)(t0 + li) * BATCH + gb1) * H + q * 8;
#pragma unroll
            for (int kf = 0; kf < 4; ++kf)
                Af[kf] = *(const half8*)(ap + kf * 32);

            f32x4 acc1[8];
#pragma unroll
            for (int ct = 0; ct < 8; ++ct) {
                acc1[ct][0] = bv1g[ct]; acc1[ct][1] = bv1g[ct];
                acc1[ct][2] = bv1g[ct]; acc1[ct][3] = bv1g[ct];
            }
#pragma unroll
            for (int ct = 0; ct < 8; ++ct) {
                const _Float16* wp = wt1h + (size_t)(n0 + ct * 16 + li) * H + q * 8;
#pragma unroll
                for (int kf = 0; kf < 4; ++kf) {
                    half8 Bfr = *(const half8*)(wp + kf * 32);
                    acc1[ct] = __builtin_amdgcn_mfma_f32_16x16x32_f16(Af[kf], Bfr, acc1[ct], 0, 0, 0);
                }
            }
            const int srow = t0 + q * 4;    // absolute step; overwrites consumed G0
#pragma unroll
            for (int ct = 0; ct < 8; ++ct)
#pragma unroll
                for (int i = 0; i < 4; ++i)
                    Gbuf[((size_t)(srow + i) * BATCH + gb1) * FOURH + n0 + ct * 16 + li] = acc1[ct][i];
            __syncthreads();
            if (tid == 0) {
                __threadfence();
                __hip_atomic_fetch_add(&g1Done[m], 1, __ATOMIC_RELEASE,
                                       __HIP_MEMORY_SCOPE_AGENT);
            }
        }
        return;
    }

    if (blockIdx.x >= 16) {
        // ================= G0 workers: free-running layer-0 GEMM =================
        const int j   = blockIdx.x - 16;    // 0..159
        const int sub = j & 31;
        const int cls = j >> 5;             // 0..4
        const int by  = sub >> 2;
        const int bx  = sub & 3;
        const int n0  = bx * BN;
        const int tm  = tid >> 5;
        const int tn  = tid & 31;

        int ar[2], aq[2], bkk[2], bq[2];
#pragma unroll
        for (int l2 = 0; l2 < 2; ++l2) {
            int fidx = tid + l2 * 512;
            ar[l2] = fidx >> 3; aq[l2] = fidx & 7;
            bkk[l2] = fidx >> 5; bq[l2] = fidx & 31;
        }
        float4 bvg = *(const float4*)&b0sum[n0 + tn * 4];

        for (int idx = cls; idx < NCHUNK; idx += 5) {
            const float* aptr[2];
#pragma unroll
            for (int l2 = 0; l2 < 2; ++l2) {
                int rl = by * BM + ar[l2];
                int b = rl >> 4;
                int t = idx * 16 + (rl & 15);
                aptr[l2] = x + ((size_t)b * SEQ + t) * 256 + aq[l2] * 4;
            }
            float acc[2][4][4];
#pragma unroll
            for (int rh = 0; rh < 2; ++rh)
#pragma unroll
                for (int i = 0; i < 4; ++i)
#pragma unroll
                    for (int jj = 0; jj < 4; ++jj) acc[rh][i][jj] = 0.f;

            for (int k0 = 0; k0 < 256; k0 += BK) {
                __syncthreads();
#pragma unroll
                for (int l2 = 0; l2 < 2; ++l2) {
                    float4 v = *(const float4*)(aptr[l2] + k0);
                    As[aq[l2] * 4 + 0][ar[l2]] = v.x;
                    As[aq[l2] * 4 + 1][ar[l2]] = v.y;
                    As[aq[l2] * 4 + 2][ar[l2]] = v.z;
                    As[aq[l2] * 4 + 3][ar[l2]] = v.w;
                }
#pragma unroll
                for (int l2 = 0; l2 < 2; ++l2) {
                    float4 v = *(const float4*)(Wt0 + (size_t)(k0 + bkk[l2]) * FOURH + n0 + bq[l2] * 4);
                    *(float4*)&Bs[bkk[l2]][bq[l2] * 4] = v;
                }
                __syncthreads();
#pragma unroll
                for (int kk = 0; kk < BK; ++kk) {
                    float a[8], bb[4];
                    *(float4*)&a[0] = *(const float4*)&As[kk][tm * 4];
                    *(float4*)&a[4] = *(const float4*)&As[kk][64 + tm * 4];
                    *(float4*)&bb[0] = *(const float4*)&Bs[kk][tn * 4];
#pragma unroll
                    for (int rh = 0; rh < 2; ++rh)
#pragma unroll
                        for (int i = 0; i < 4; ++i)
#pragma unroll
                            for (int jj = 0; jj < 4; ++jj)
                                acc[rh][i][jj] = fmaf(a[rh * 4 + i], bb[jj], acc[rh][i][jj]);
                }
            }
#pragma unroll
            for (int rh = 0; rh < 2; ++rh)
#pragma unroll
                for (int i = 0; i < 4; ++i) {
                    int rl = by * BM + rh * 64 + tm * 4 + i;
                    int b = rl >> 4;
                    int t = idx * 16 + (rl & 15);
                    float* gp = Gbuf + ((size_t)t * BATCH + b) * FOURH + n0 + tn * 4;
                    float4 o = make_float4(acc[rh][i][0] + bvg.x, acc[rh][i][1] + bvg.y,
                                           acc[rh][i][2] + bvg.z, acc[rh][i][3] + bvg.w);
                    *(float4*)gp = o;
                }
            __syncthreads();
            if (tid == 0) {
                __threadfence();
                __hip_atomic_fetch_add(&chunkDone[idx], 1, __ATOMIC_RELEASE,
                                       __HIP_MEMORY_SCOPE_AGENT);
            }
        }
        return;
    }

    // ================= scan blocks =================
    const int w  = tid >> 6;
    const int l  = tid & 63;
    const int li = l & 15;
    const int q  = l >> 4;
    const int u  = 16 * w + li;                 // owned hidden unit (C col)
    const int b0 = q * 2;                       // local batch for C-row r=0
    const int ab = ((li >> 2) * 2) + (li & 1);  // A-row -> local batch (dup map)

#define WAIT_FLAG(ptr, tgtv)                                                   \
    do {                                                                       \
        if (tid == 0) {                                                        \
            while (__hip_atomic_load((ptr), __ATOMIC_RELAXED,                  \
                                     __HIP_MEMORY_SCOPE_AGENT) < (tgtv))       \
                __builtin_amdgcn_s_sleep(4);                                   \
            (void)__hip_atomic_load((ptr), __ATOMIC_ACQUIRE,                   \
                                    __HIP_MEMORY_SCOPE_AGENT);                 \
        }                                                                      \
        __syncthreads();                                                       \
    } while (0)

// Scan step: slot min(S+4, 2047) prefetched into GR (clamped overrun values
// are never consumed), 16 MFMAs (4 gates x K=128), activations, LDS handoff.
#define SCAN_STEP(S, PB, GR, BFARR, STORE_STMT)                                   \
    {                                                                             \
        half8 Afr[4];                                                             \
        _Pragma("unroll")                                                         \
        for (int kf = 0; kf < 4; ++kf)                                            \
            Afr[kf] = *(const half8*)&hbuf[PB][ab][kf * 32 + q * 8];              \
        f32x4 acc[4];                                                             \
        _Pragma("unroll")                                                         \
        for (int tl = 0; tl < 4; ++tl) {                                          \
            acc[tl][0] = GR[tl * 2 + 0]; acc[tl][1] = GR[tl * 2 + 1];             \
            acc[tl][2] = 0.f;            acc[tl][3] = 0.f;                        \
        }                                                                         \
        {                                                                         \
            int sl_ = (S) + 4; if (sl_ > TC - 1) sl_ = TC - 1;                    \
            const float* gp_ = Gbuf + (size_t)sl_ * GSTRIDE;                      \
            _Pragma("unroll")                                                     \
            for (int tl = 0; tl < 4; ++tl) {                                      \
                GR[tl * 2 + 0] = gp_[boff0 + tl * H];                             \
                GR[tl * 2 + 1] = gp_[boff1 + tl * H];                             \
            }                                                                     \
        }                                                                         \
        _Pragma("unroll")                                                         \
        for (int kf = 0; kf < 4; ++kf)                                            \
            _Pragma("unroll")                                                     \
            for (int tl = 0; tl < 4; ++tl)                                        \
                acc[tl] = __builtin_amdgcn_mfma_f32_16x16x32_f16(Afr[kf], BFARR[tl][kf], acc[tl], 0, 0, 0); \
        {                                                                         \
            float ig = sigmoid_f(acc[0][0]);                                      \
            float fg = sigmoid_f(acc[1][0]);                                      \
            float gg = tanh_f(acc[2][0]);                                         \
            float og = sigmoid_f(acc[3][0]);                                      \
            c0 = fmaf(fg, c0, ig * gg);                                           \
            h0 = og * tanh_f(c0);                                                 \
            float ig1 = sigmoid_f(acc[0][1]);                                     \
            float fg1 = sigmoid_f(acc[1][1]);                                     \
            float gg1 = tanh_f(acc[2][1]);                                        \
            float og1 = sigmoid_f(acc[3][1]);                                     \
            c1 = fmaf(fg1, c1, ig1 * gg1);                                        \
            h1v = og1 * tanh_f(c1);                                               \
        }                                                                         \
        hbuf[PB ^ 1][b0][u]     = (_Float16)h0;                                   \
        hbuf[PB ^ 1][b0 + 1][u] = (_Float16)h1v;                                  \
        STORE_STMT                                                                \
        LDS_BARRIER();                                                            \
    }

    const int g = (blockIdx.x < 8) ? blockIdx.x : blockIdx.x - 8;
    const int boff0 = (8 * g + b0) * FOURH + u;
    const int boff1 = boff0 + FOURH;

    if (blockIdx.x < 8) {
        // ================= producer: layer 0 =================
        half8 Bf[4][4];
#pragma unroll
        for (int tl = 0; tl < 4; ++tl)
#pragma unroll
            for (int kf = 0; kf < 4; ++kf) {
                const float* wp = Whh0 + (size_t)(tl * 128 + u) * H + kf * 32 + q * 8;
                float4 v0 = *(const float4*)wp;
                float4 v1 = *(const float4*)(wp + 4);
                half8 b;
                b[0] = (_Float16)v0.x; b[1] = (_Float16)v0.y;
                b[2] = (_Float16)v0.z; b[3] = (_Float16)v0.w;
                b[4] = (_Float16)v1.x; b[5] = (_Float16)v1.y;
                b[6] = (_Float16)v1.z; b[7] = (_Float16)v1.w;
                Bf[tl][kf] = b;
            }

        float c0 = 0.f, c1 = 0.f, h0 = 0.f, h1v = 0.f;
        hbuf[0][b0][u]     = (_Float16)0.f;
        hbuf[0][b0 + 1][u] = (_Float16)0.f;

        WAIT_FLAG(&chunkDone[0], 32);     // first G0 chunk ready (orders hbuf init too)

        float Ga[8], Gb[8], Gc[8], Gd[8];
#pragma unroll
        for (int tl = 0; tl < 4; ++tl) {
            Ga[tl * 2 + 0] = Gbuf[(size_t)0 * GSTRIDE + boff0 + tl * H];
            Ga[tl * 2 + 1] = Gbuf[(size_t)0 * GSTRIDE + boff1 + tl * H];
            Gb[tl * 2 + 0] = Gbuf[(size_t)1 * GSTRIDE + boff0 + tl * H];
            Gb[tl * 2 + 1] = Gbuf[(size_t)1 * GSTRIDE + boff1 + tl * H];
            Gc[tl * 2 + 0] = Gbuf[(size_t)2 * GSTRIDE + boff0 + tl * H];
            Gc[tl * 2 + 1] = Gbuf[(size_t)2 * GSTRIDE + boff1 + tl * H];
            Gd[tl * 2 + 0] = Gbuf[(size_t)3 * GSTRIDE + boff0 + tl * H];
            Gd[tl * 2 + 1] = Gbuf[(size_t)3 * GSTRIDE + boff1 + tl * H];
        }

        _Float16* php = h1p + (size_t)(8 * g + b0) * H + u;   // +step*8192

#define P_STORE { php[0] = (_Float16)h0; php[128] = (_Float16)h1v; php += BATCH * H; }

        for (int s4 = 0; s4 < TC; s4 += 4) {
            if ((s4 & 15) == 0) {
                int k = (s4 >> 4) + 1;               // prefetch spills into next chunk
                if (k > NCHUNK - 1) k = NCHUNK - 1;
                WAIT_FLAG(&chunkDone[k], 32);
            }
            SCAN_STEP(s4 + 0, 0, Ga, Bf, P_STORE)
            SCAN_STEP(s4 + 1, 1, Gb, Bf, P_STORE)
            SCAN_STEP(s4 + 2, 0, Gc, Bf, P_STORE)
            SCAN_STEP(s4 + 3, 1, Gd, Bf, P_STORE)
            if ((s4 & 15) == 12) {
                __threadfence();            // make h1p stores device-visible
                __syncthreads();            // all waves fenced before flag
                if (tid == 0)
                    __hip_atomic_store(&prodF[g], s4 + 4, __ATOMIC_RELEASE,
                                       __HIP_MEMORY_SCOPE_AGENT);
            }
        }
#undef P_STORE
    } else {
        // ================= consumer: layer 1 (recurrent only) =================
        half8 Bf[4][4];   // Whh1 fragments only
#pragma unroll
        for (int tl = 0; tl < 4; ++tl)
#pragma unroll
            for (int kf = 0; kf < 4; ++kf) {
                const float* wp = Whh1 + (size_t)(tl * 128 + u) * H + kf * 32 + q * 8;
                float4 v0 = *(const float4*)wp;
                float4 v1 = *(const float4*)(wp + 4);
                half8 b;
                b[0] = (_Float16)v0.x; b[1] = (_Float16)v0.y;
                b[2] = (_Float16)v0.z; b[3] = (_Float16)v0.w;
                b[4] = (_Float16)v1.x; b[5] = (_Float16)v1.y;
                b[6] = (_Float16)v1.z; b[7] = (_Float16)v1.w;
                Bf[tl][kf] = b;
            }

        float c0 = 0.f, c1 = 0.f, h0, h1v;
        hbuf[0][b0][u]     = (_Float16)0.f;
        hbuf[0][b0 + 1][u] = (_Float16)0.f;

        float* op0 = out + (size_t)(8 * g + b0) * SEQ * H + u;      // +step*H
        float* op1 = out + (size_t)(8 * g + b0 + 1) * SEQ * H + u;

        WAIT_FLAG(&prodF[g], 96);         // initial lag: keeps g1Done waits
                                          // off the steady-state critical path
        WAIT_FLAG(&g1Done[0], 32);        // chunk 0 G1-written (orders hbuf init)

        float Ga[8], Gb[8], Gc[8], Gd[8];
#pragma unroll
        for (int tl = 0; tl < 4; ++tl) {
            Ga[tl * 2 + 0] = Gbuf[(size_t)0 * GSTRIDE + boff0 + tl * H];
            Ga[tl * 2 + 1] = Gbuf[(size_t)0 * GSTRIDE + boff1 + tl * H];
            Gb[tl * 2 + 0] = Gbuf[(size_t)1 * GSTRIDE + boff0 + tl * H];
            Gb[tl * 2 + 1] = Gbuf[(size_t)1 * GSTRIDE + boff1 + tl * H];
            Gc[tl * 2 + 0] = Gbuf[(size_t)2 * GSTRIDE + boff0 + tl * H];
            Gc[tl * 2 + 1] = Gbuf[(size_t)2 * GSTRIDE + boff1 + tl * H];
            Gd[tl * 2 + 0] = Gbuf[(size_t)3 * GSTRIDE + boff0 + tl * H];
            Gd[tl * 2 + 1] = Gbuf[(size_t)3 * GSTRIDE + boff1 + tl * H];
        }

#define C_STORE { op0[0] = h0; op1[0] = h1v; op0 += H; op1 += H; }

        for (int s4 = 0; s4 < TC; s4 += 4) {
            if ((s4 & 15) == 0) {
                int k = (s4 >> 4) + 1;
                if (k > NCHUNK - 1) k = NCHUNK - 1;
                WAIT_FLAG(&g1Done[k], 32);
            }
            SCAN_STEP(s4 + 0, 0, Ga, Bf, C_STORE)
            SCAN_STEP(s4 + 1, 1, Gb, Bf, C_STORE)
            SCAN_STEP(s4 + 2, 0, Gc, Bf, C_STORE)
            SCAN_STEP(s4 + 3, 1, Gd, Bf, C_STORE)
        }
#undef C_STORE
    }
#undef WAIT_FLAG
#undef SCAN_STEP
}

// ---------------- launch ----------------
extern "C" void kernel_launch(void* const* d_in, const int* in_sizes, int n_in,
                              void* d_out, int out_size, void* d_ws, size_t ws_size,
                              hipStream_t stream) {
    const float* x    = (const float*)d_in[0];
    const float* Wih0 = (const float*)d_in[1];
    const float* Whh0 = (const float*)d_in[2];
    const float* bih0 = (const float*)d_in[3];
    const float* bhh0 = (const float*)d_in[4];
    const float* Wih1 = (const float*)d_in[5];
    const float* Whh1 = (const float*)d_in[6];
    const float* bih1 = (const float*)d_in[7];
    const float* bhh1 = (const float*)d_in[8];
    float* out = (float*)d_out;

    char* ws = (char*)d_ws;
    size_t off = 0;
    auto carve = [&](size_t bytes) -> char* {
        char* p = ws + off;
        off += (bytes + 255) & ~(size_t)255;
        return p;
    };

    float*     Wt0   = (float*)carve(256 * 512 * 4);
    float*     b0v   = (float*)carve(512 * 4);
    float*     b1v   = (float*)carve(512 * 4);
    _Float16*  wt1h  = (_Float16*)carve(65536 * 2);
    _Float16*  h1p   = (_Float16*)carve((size_t)SEQ * BATCH * H * 2);    // 33.6 MB
    int*       flags = (int*)carve(272 * 4);
    // t-major phase-reused gate buffer; prefetch overruns clamped -> no slack
    float*     gbuf  = (float*)carve((size_t)SEQ * GSTRIDE * 4);         // 268.4 MB

    prep_kernel<<<774, 256, 0, stream>>>(Wih0, bih0, bhh0, bih1, bhh1, Wih1,
                                         Wt0, b0v, b1v, wt1h, flags);

    // single persistent kernel: 4-stage DAG pipeline, phase-reused gbuf
    lstm_fused_kernel<<<240, 512, 0, stream>>>(x, Wt0, b0v, gbuf,
                                               Whh0, wt1h, Whh1, b1v,
                                               h1p, out, flags);
}

// Round 9
// 2361.407 us; speedup vs baseline: 1.0579x; 1.0579x over previous
//
#include <hip/hip_runtime.h>
#include <hip/hip_bf16.h>

#define H 128
#define FOURH 512
#define BATCH 64
#define SEQ 2048
#define TC SEQ
#define NCHUNK 128                 // 2048 / 16 steps per chunk
#define GSTRIDE (BATCH * FOURH)    // floats per t-major slot [64][512]

typedef _Float16 half8 __attribute__((ext_vector_type(8)));
typedef float f32x4 __attribute__((ext_vector_type(4)));

// ---- prep: transpose Wih0 -> [K][512], fp16 Wih1, sum biases, zero flags ----
__global__ void prep_kernel(const float* __restrict__ Wih0,
                            const float* __restrict__ bih0, const float* __restrict__ bhh0,
                            const float* __restrict__ bih1, const float* __restrict__ bhh1,
                            const float* __restrict__ Wih1,
                            float* __restrict__ Wt0,
                            float* __restrict__ b0, float* __restrict__ b1,
                            _Float16* __restrict__ wt1h,
                            int* __restrict__ flags) {
    int id = blockIdx.x * 256 + threadIdx.x;
    const int N0 = 256 * 512;
    if (id < N0) {
        int k = id >> 9, n = id & 511;
        Wt0[id] = Wih0[n * 256 + k];
    } else if (id < N0 + 512) {
        int i = id - N0;
        b0[i] = bih0[i] + bhh0[i];
    } else if (id < N0 + 1024) {
        int i = id - (N0 + 512);
        b1[i] = bih1[i] + bhh1[i];
    } else if (id < N0 + 1024 + 65536) {
        int i = id - (N0 + 1024);
        wt1h[i] = (_Float16)Wih1[i];          // same RNE rounding the consumer used
    } else if (id < N0 + 1024 + 65536 + 272) {
        flags[id - (N0 + 1024 + 65536)] = 0;
    }
}

// ---------------- fp32 GEMM0: Gbuf[(t*64+b)*512+n] = x@Wih0^T + b0 ----------
#define BM 128
#define BN 128
#define BK 32

__global__ __launch_bounds__(256) void gemm_bias_kernel(
    const float* __restrict__ A, int lda, int rowsPerBatch, int t0,
    const float* __restrict__ Bt, const float* __restrict__ bias,
    float* __restrict__ G, int K, int tcShift)
{
    __shared__ float As[BK][BM + 4];
    __shared__ float Bs[BK][BN];

    const int tid = threadIdx.x;
    const int m0 = blockIdx.y * BM;
    const int n0 = blockIdx.x * BN;
    const int tm = tid >> 4;
    const int tn = tid & 15;
    const int tcMask = (1 << tcShift) - 1;

    const float* aptr[4];
    int ar[4], aq[4];
#pragma unroll
    for (int l = 0; l < 4; ++l) {
        int fidx = tid + l * 256;
        int r = fidx >> 3, q = fidx & 7;
        ar[l] = r; aq[l] = q;
        int m = m0 + r;
        int bi = m >> tcShift;
        int tl = m & tcMask;
        aptr[l] = A + ((size_t)bi * rowsPerBatch + t0 + tl) * lda + q * 4;
    }
    int bkk[4], bq[4];
#pragma unroll
    for (int l = 0; l < 4; ++l) {
        int fidx = tid + l * 256;
        bkk[l] = fidx >> 5; bq[l] = fidx & 31;
    }

    float acc[2][2][4][4];
#pragma unroll
    for (int ri = 0; ri < 2; ++ri)
#pragma unroll
        for (int ci = 0; ci < 2; ++ci)
#pragma unroll
            for (int i = 0; i < 4; ++i)
#pragma unroll
                for (int j = 0; j < 4; ++j) acc[ri][ci][i][j] = 0.f;

    for (int k0 = 0; k0 < K; k0 += BK) {
        __syncthreads();
#pragma unroll
        for (int l = 0; l < 4; ++l) {
            float4 v = *(const float4*)(aptr[l] + k0);
            As[aq[l] * 4 + 0][ar[l]] = v.x;
            As[aq[l] * 4 + 1][ar[l]] = v.y;
            As[aq[l] * 4 + 2][ar[l]] = v.z;
            As[aq[l] * 4 + 3][ar[l]] = v.w;
        }
#pragma unroll
        for (int l = 0; l < 4; ++l) {
            float4 v = *(const float4*)(Bt + (size_t)(k0 + bkk[l]) * FOURH + n0 + bq[l] * 4);
            *(float4*)&Bs[bkk[l]][bq[l] * 4] = v;
        }
        __syncthreads();
#pragma unroll
        for (int kk = 0; kk < BK; ++kk) {
            float a[8], bb[8];
            *(float4*)&a[0] = *(const float4*)&As[kk][tm * 4];
            *(float4*)&a[4] = *(const float4*)&As[kk][64 + tm * 4];
            *(float4*)&bb[0] = *(const float4*)&Bs[kk][tn * 4];
            *(float4*)&bb[4] = *(const float4*)&Bs[kk][64 + tn * 4];
#pragma unroll
            for (int ri = 0; ri < 2; ++ri)
#pragma unroll
                for (int i = 0; i < 4; ++i)
#pragma unroll
                    for (int ci = 0; ci < 2; ++ci)
#pragma unroll
                        for (int j = 0; j < 4; ++j)
                            acc[ri][ci][i][j] = fmaf(a[ri * 4 + i], bb[ci * 4 + j], acc[ri][ci][i][j]);
        }
    }

    float4 bv0 = *(const float4*)&bias[n0 + tn * 4];
    float4 bv1 = *(const float4*)&bias[n0 + 64 + tn * 4];
#pragma unroll
    for (int ri = 0; ri < 2; ++ri)
#pragma unroll
        for (int i = 0; i < 4; ++i) {
            int m = m0 + ri * 64 + tm * 4 + i;
            int bi = m >> tcShift;
            int tl = m & tcMask;
            float* gp = G + ((size_t)tl * BATCH + bi) * FOURH + n0;   // t-major slot
            float4 o0 = make_float4(acc[ri][0][i][0] + bv0.x, acc[ri][0][i][1] + bv0.y,
                                    acc[ri][0][i][2] + bv0.z, acc[ri][0][i][3] + bv0.w);
            float4 o1 = make_float4(acc[ri][1][i][0] + bv1.x, acc[ri][1][i][1] + bv1.y,
                                    acc[ri][1][i][2] + bv1.z, acc[ri][1][i][3] + bv1.w);
            *(float4*)(gp + tn * 4) = o0;
            *(float4*)(gp + 64 + tn * 4) = o1;
        }
}

// ---------------- fused scan + G1 offload ----------------
__device__ __forceinline__ float sigmoid_f(float x) {
    return __builtin_amdgcn_rcpf(1.f + __expf(-x));
}
__device__ __forceinline__ float tanh_f(float x) {
    return 1.f - 2.f * __builtin_amdgcn_rcpf(__expf(2.f * x) + 1.f);
}

// Light barrier: LDS handoff only. Global loads/stores stay in flight across it.
#define LDS_BARRIER()                                                \
    do {                                                             \
        asm volatile("s_waitcnt lgkmcnt(0)" ::: "memory");           \
        __builtin_amdgcn_s_barrier();                                \
        __builtin_amdgcn_sched_barrier(0);                           \
    } while (0)

// PHASE-REUSED Gbuf (proven bit-exact + deterministic in R8), G1-only army:
// slot lifecycle  gemm0-write -> producer-read -> G1-write -> consumer-read.
//   producer: free-runs (Gbuf fully written by prior kernel, stream order);
//             publishes prodF every 16 steps (fence+release).
//   G1 worker chunk m: waits prodF>=16(m+1). Producer's last touch of chunk-m
//             slots is the step-(16m+11) prefetch, consumed at step 16m+15,
//             which happens-before the prodF release G1 acquires.
//   consumer: initial 96-step lag (prodF>=96), then gated on g1Done[k].
// Wait graph: producer -> (), G1 -> producer, consumer -> G1. A chain:
// deadlock-free, single-writer per (slot,phase), replay-deterministic.
// No G0 army: R3/R5/R8 all showed bulk-GEMM concurrency degrades the
// latency-chain scan more than it saves. GEMM0 stays a serial prologue.
__global__ __launch_bounds__(512, 2) void lstm_fused_kernel(
    float* __restrict__ Gbuf,         // [T][64][512] phase-reused gate buffer
    const float* __restrict__ Whh0,   // [512][128]
    const _Float16* __restrict__ wt1h,// [512][128] fp16 Wih1
    const float* __restrict__ Whh1,   // [512][128]
    const float* __restrict__ b1,     // [512] summed layer-1 biases
    _Float16* __restrict__ h1p,       // [T][64][128] fp16 layer-0 hidden
    float* __restrict__ out,          // [64][T][128] fp32 layer-1 hidden
    int* __restrict__ flags)          // [8]prodF [8]pad [128]pad [128]g1Done
{
    const int tid = threadIdx.x;

    int* prodF  = flags;
    int* g1Done = flags + 144;

    __shared__ _Float16 hbuf[2][8][136];   // scan recurrent h, fp16, dbuf

    if (blockIdx.x >= 16) {
        // ================= G1 workers: layer-1 input projection =================
        const int j   = blockIdx.x - 16;    // 0..63
        const int sub = j & 31;
        const int cls = j >> 5;             // 0..1
        const int by  = sub >> 2;           // batch group 0..7
        const int bx  = sub & 3;
        const int n0  = bx * 128;
        const int wv  = tid >> 6;           // wave -> batch within group
        const int l   = tid & 63;
        const int li  = l & 15;
        const int q   = l >> 4;
        const int gb1 = 8 * by + wv;

        float bv1g[8];
#pragma unroll
        for (int ct = 0; ct < 8; ++ct) bv1g[ct] = b1[n0 + ct * 16 + li];

        for (int m = cls; m < NCHUNK; m += 2) {
            if (tid == 0) {
                while (__hip_atomic_load(&prodF[by], __ATOMIC_RELAXED,
                                         __HIP_MEMORY_SCOPE_AGENT) < 16 * (m + 1))
                    __builtin_amdgcn_s_sleep(4);
                (void)__hip_atomic_load(&prodF[by], __ATOMIC_ACQUIRE,
                                        __HIP_MEMORY_SCOPE_AGENT);
            }
            __syncthreads();

            const int t0 = m * 16;
            half8 Af[4];
            const _Float16* ap = h1p + ((size_t)(t0 + li) * BATCH + gb1) * H + q * 8;
#pragma unroll
            for (int kf = 0; kf < 4; ++kf)
                Af[kf] = *(const half8*)(ap + kf * 32);

            f32x4 acc1[8];
#pragma unroll
            for (int ct = 0; ct < 8; ++ct) {
                acc1[ct][0] = bv1g[ct]; acc1[ct][1] = bv1g[ct];
                acc1[ct][2] = bv1g[ct]; acc1[ct][3] = bv1g[ct];
            }
#pragma unroll
            for (int ct = 0; ct < 8; ++ct) {
                const _Float16* wp = wt1h + (size_t)(n0 + ct * 16 + li) * H + q * 8;
#pragma unroll
                for (int kf = 0; kf < 4; ++kf) {
                    half8 Bfr = *(const half8*)(wp + kf * 32);
                    acc1[ct] = __builtin_amdgcn_mfma_f32_16x16x32_f16(Af[kf], Bfr, acc1[ct], 0, 0, 0);
                }
            }
            const int srow = t0 + q * 4;    // absolute step; overwrites consumed G0
#pragma unroll
            for (int ct = 0; ct < 8; ++ct)
#pragma unroll
                for (int i = 0; i < 4; ++i)
                    Gbuf[((size_t)(srow + i) * BATCH + gb1) * FOURH + n0 + ct * 16 + li] = acc1[ct][i];
            __syncthreads();
            if (tid == 0) {
                __threadfence();
                __hip_atomic_fetch_add(&g1Done[m], 1, __ATOMIC_RELEASE,
                                       __HIP_MEMORY_SCOPE_AGENT);
            }
        }
        return;
    }

    // ================= scan blocks =================
    const int w  = tid >> 6;
    const int l  = tid & 63;
    const int li = l & 15;
    const int q  = l >> 4;
    const int u  = 16 * w + li;                 // owned hidden unit (C col)
    const int b0 = q * 2;                       // local batch for C-row r=0
    const int ab = ((li >> 2) * 2) + (li & 1);  // A-row -> local batch (dup map)

#define WAIT_FLAG(ptr, tgtv)                                                   \
    do {                                                                       \
        if (tid == 0) {                                                        \
            while (__hip_atomic_load((ptr), __ATOMIC_RELAXED,                  \
                                     __HIP_MEMORY_SCOPE_AGENT) < (tgtv))       \
                __builtin_amdgcn_s_sleep(4);                                   \
            (void)__hip_atomic_load((ptr), __ATOMIC_ACQUIRE,                   \
                                    __HIP_MEMORY_SCOPE_AGENT);                 \
        }                                                                      \
        __syncthreads();                                                       \
    } while (0)

// Scan step: slot min(S+4, 2047) prefetched into GR (clamped overrun values
// are never consumed), 16 MFMAs (4 gates x K=128), activations, LDS handoff.
#define SCAN_STEP(S, PB, GR, BFARR, STORE_STMT)                                   \
    {                                                                             \
        half8 Afr[4];                                                             \
        _Pragma("unroll")                                                         \
        for (int kf = 0; kf < 4; ++kf)                                            \
            Afr[kf] = *(const half8*)&hbuf[PB][ab][kf * 32 + q * 8];              \
        f32x4 acc[4];                                                             \
        _Pragma("unroll")                                                         \
        for (int tl = 0; tl < 4; ++tl) {                                          \
            acc[tl][0] = GR[tl * 2 + 0]; acc[tl][1] = GR[tl * 2 + 1];             \
            acc[tl][2] = 0.f;            acc[tl][3] = 0.f;                        \
        }                                                                         \
        {                                                                         \
            int sl_ = (S) + 4; if (sl_ > TC - 1) sl_ = TC - 1;                    \
            const float* gp_ = Gbuf + (size_t)sl_ * GSTRIDE;                      \
            _Pragma("unroll")                                                     \
            for (int tl = 0; tl < 4; ++tl) {                                      \
                GR[tl * 2 + 0] = gp_[boff0 + tl * H];                             \
                GR[tl * 2 + 1] = gp_[boff1 + tl * H];                             \
            }                                                                     \
        }                                                                         \
        _Pragma("unroll")                                                         \
        for (int kf = 0; kf < 4; ++kf)                                            \
            _Pragma("unroll")                                                     \
            for (int tl = 0; tl < 4; ++tl)                                        \
                acc[tl] = __builtin_amdgcn_mfma_f32_16x16x32_f16(Afr[kf], BFARR[tl][kf], acc[tl], 0, 0, 0); \
        {                                                                         \
            float ig = sigmoid_f(acc[0][0]);                                      \
            float fg = sigmoid_f(acc[1][0]);                                      \
            float gg = tanh_f(acc[2][0]);                                         \
            float og = sigmoid_f(acc[3][0]);                                      \
            c0 = fmaf(fg, c0, ig * gg);                                           \
            h0 = og * tanh_f(c0);                                                 \
            float ig1 = sigmoid_f(acc[0][1]);                                     \
            float fg1 = sigmoid_f(acc[1][1]);                                     \
            float gg1 = tanh_f(acc[2][1]);                                        \
            float og1 = sigmoid_f(acc[3][1]);                                     \
            c1 = fmaf(fg1, c1, ig1 * gg1);                                        \
            h1v = og1 * tanh_f(c1);                                               \
        }                                                                         \
        hbuf[PB ^ 1][b0][u]     = (_Float16)h0;                                   \
        hbuf[PB ^ 1][b0 + 1][u] = (_Float16)h1v;                                  \
        STORE_STMT                                                                \
        LDS_BARRIER();                                                            \
    }

    const int g = (blockIdx.x < 8) ? blockIdx.x : blockIdx.x - 8;
    const int boff0 = (8 * g + b0) * FOURH + u;
    const int boff1 = boff0 + FOURH;

    if (blockIdx.x < 8) {
        // ================= producer: layer 0 (free-running) =================
        half8 Bf[4][4];
#pragma unroll
        for (int tl = 0; tl < 4; ++tl)
#pragma unroll
            for (int kf = 0; kf < 4; ++kf) {
                const float* wp = Whh0 + (size_t)(tl * 128 + u) * H + kf * 32 + q * 8;
                float4 v0 = *(const float4*)wp;
                float4 v1 = *(const float4*)(wp + 4);
                half8 b;
                b[0] = (_Float16)v0.x; b[1] = (_Float16)v0.y;
                b[2] = (_Float16)v0.z; b[3] = (_Float16)v0.w;
                b[4] = (_Float16)v1.x; b[5] = (_Float16)v1.y;
                b[6] = (_Float16)v1.z; b[7] = (_Float16)v1.w;
                Bf[tl][kf] = b;
            }

        float c0 = 0.f, c1 = 0.f, h0 = 0.f, h1v = 0.f;
        hbuf[0][b0][u]     = (_Float16)0.f;
        hbuf[0][b0 + 1][u] = (_Float16)0.f;
        __syncthreads();                  // hbuf init visible to all waves

        float Ga[8], Gb[8], Gc[8], Gd[8];
#pragma unroll
        for (int tl = 0; tl < 4; ++tl) {
            Ga[tl * 2 + 0] = Gbuf[(size_t)0 * GSTRIDE + boff0 + tl * H];
            Ga[tl * 2 + 1] = Gbuf[(size_t)0 * GSTRIDE + boff1 + tl * H];
            Gb[tl * 2 + 0] = Gbuf[(size_t)1 * GSTRIDE + boff0 + tl * H];
            Gb[tl * 2 + 1] = Gbuf[(size_t)1 * GSTRIDE + boff1 + tl * H];
            Gc[tl * 2 + 0] = Gbuf[(size_t)2 * GSTRIDE + boff0 + tl * H];
            Gc[tl * 2 + 1] = Gbuf[(size_t)2 * GSTRIDE + boff1 + tl * H];
            Gd[tl * 2 + 0] = Gbuf[(size_t)3 * GSTRIDE + boff0 + tl * H];
            Gd[tl * 2 + 1] = Gbuf[(size_t)3 * GSTRIDE + boff1 + tl * H];
        }

        _Float16* php = h1p + (size_t)(8 * g + b0) * H + u;   // +step*8192

#define P_STORE { php[0] = (_Float16)h0; php[128] = (_Float16)h1v; php += BATCH * H; }

        for (int s4 = 0; s4 < TC; s4 += 4) {
            SCAN_STEP(s4 + 0, 0, Ga, Bf, P_STORE)
            SCAN_STEP(s4 + 1, 1, Gb, Bf, P_STORE)
            SCAN_STEP(s4 + 2, 0, Gc, Bf, P_STORE)
            SCAN_STEP(s4 + 3, 1, Gd, Bf, P_STORE)
            if ((s4 & 15) == 12) {
                __threadfence();            // make h1p stores device-visible
                __syncthreads();            // all waves fenced before flag
                if (tid == 0)
                    __hip_atomic_store(&prodF[g], s4 + 4, __ATOMIC_RELEASE,
                                       __HIP_MEMORY_SCOPE_AGENT);
            }
        }
#undef P_STORE
    } else {
        // ================= consumer: layer 1 (recurrent only) =================
        half8 Bf[4][4];   // Whh1 fragments only
#pragma unroll
        for (int tl = 0; tl < 4; ++tl)
#pragma unroll
            for (int kf = 0; kf < 4; ++kf) {
                const float* wp = Whh1 + (size_t)(tl * 128 + u) * H + kf * 32 + q * 8;
                float4 v0 = *(const float4*)wp;
                float4 v1 = *(const float4*)(wp + 4);
                half8 b;
                b[0] = (_Float16)v0.x; b[1] = (_Float16)v0.y;
                b[2] = (_Float16)v0.z; b[3] = (_Float16)v0.w;
                b[4] = (_Float16)v1.x; b[5] = (_Float16)v1.y;
                b[6] = (_Float16)v1.z; b[7] = (_Float16)v1.w;
                Bf[tl][kf] = b;
            }

        float c0 = 0.f, c1 = 0.f, h0, h1v;
        hbuf[0][b0][u]     = (_Float16)0.f;
        hbuf[0][b0 + 1][u] = (_Float16)0.f;

        float* op0 = out + (size_t)(8 * g + b0) * SEQ * H + u;      // +step*H
        float* op1 = out + (size_t)(8 * g + b0 + 1) * SEQ * H + u;

        WAIT_FLAG(&prodF[g], 96);         // initial lag: steady-state g1Done
                                          // waits stay off the critical path
        WAIT_FLAG(&g1Done[0], 32);        // chunk 0 G1-written (orders hbuf init)

        float Ga[8], Gb[8], Gc[8], Gd[8];
#pragma unroll
        for (int tl = 0; tl < 4; ++tl) {
            Ga[tl * 2 + 0] = Gbuf[(size_t)0 * GSTRIDE + boff0 + tl * H];
            Ga[tl * 2 + 1] = Gbuf[(size_t)0 * GSTRIDE + boff1 + tl * H];
            Gb[tl * 2 + 0] = Gbuf[(size_t)1 * GSTRIDE + boff0 + tl * H];
            Gb[tl * 2 + 1] = Gbuf[(size_t)1 * GSTRIDE + boff1 + tl * H];
            Gc[tl * 2 + 0] = Gbuf[(size_t)2 * GSTRIDE + boff0 + tl * H];
            Gc[tl * 2 + 1] = Gbuf[(size_t)2 * GSTRIDE + boff1 + tl * H];
            Gd[tl * 2 + 0] = Gbuf[(size_t)3 * GSTRIDE + boff0 + tl * H];
            Gd[tl * 2 + 1] = Gbuf[(size_t)3 * GSTRIDE + boff1 + tl * H];
        }

#define C_STORE { op0[0] = h0; op1[0] = h1v; op0 += H; op1 += H; }

        for (int s4 = 0; s4 < TC; s4 += 4) {
            if ((s4 & 15) == 0) {
                int k = (s4 >> 4) + 1;
                if (k > NCHUNK - 1) k = NCHUNK - 1;
                WAIT_FLAG(&g1Done[k], 32);
            }
            SCAN_STEP(s4 + 0, 0, Ga, Bf, C_STORE)
            SCAN_STEP(s4 + 1, 1, Gb, Bf, C_STORE)
            SCAN_STEP(s4 + 2, 0, Gc, Bf, C_STORE)
            SCAN_STEP(s4 + 3, 1, Gd, Bf, C_STORE)
        }
#undef C_STORE
    }
#undef WAIT_FLAG
#undef SCAN_STEP
}

// ---------------- launch ----------------
extern "C" void kernel_launch(void* const* d_in, const int* in_sizes, int n_in,
                              void* d_out, int out_size, void* d_ws, size_t ws_size,
                              hipStream_t stream) {
    const float* x    = (const float*)d_in[0];
    const float* Wih0 = (const float*)d_in[1];
    const float* Whh0 = (const float*)d_in[2];
    const float* bih0 = (const float*)d_in[3];
    const float* bhh0 = (const float*)d_in[4];
    const float* Wih1 = (const float*)d_in[5];
    const float* Whh1 = (const float*)d_in[6];
    const float* bih1 = (const float*)d_in[7];
    const float* bhh1 = (const float*)d_in[8];
    float* out = (float*)d_out;

    char* ws = (char*)d_ws;
    size_t off = 0;
    auto carve = [&](size_t bytes) -> char* {
        char* p = ws + off;
        off += (bytes + 255) & ~(size_t)255;
        return p;
    };

    float*     Wt0   = (float*)carve(256 * 512 * 4);
    float*     b0v   = (float*)carve(512 * 4);
    float*     b1v   = (float*)carve(512 * 4);
    _Float16*  wt1h  = (_Float16*)carve(65536 * 2);
    _Float16*  h1p   = (_Float16*)carve((size_t)SEQ * BATCH * H * 2);    // 33.6 MB
    int*       flags = (int*)carve(272 * 4);
    // t-major phase-reused gate buffer; prefetch overruns clamped -> no slack
    float*     gbuf  = (float*)carve((size_t)SEQ * GSTRIDE * 4);         // 268.4 MB

    prep_kernel<<<774, 256, 0, stream>>>(Wih0, bih0, bhh0, bih1, bhh1, Wih1,
                                         Wt0, b0v, b1v, wt1h, flags);

    // serial layer-0 input GEMM over the full sequence (t-major output)
    dim3 ggrid(FOURH / BN, (BATCH * SEQ) / BM);
    gemm_bias_kernel<<<ggrid, 256, 0, stream>>>(x, 256, SEQ, 0, Wt0, b0v, gbuf, 256, 11);

    // fused scan: 8 producers + 8 consumers + 64 G1 workers (phase-reused gbuf)
    lstm_fused_kernel<<<80, 512, 0, stream>>>(gbuf, Whh0, wt1h, Whh1, b1v,
                                              h1p, out, flags);
}

// Round 10
// 2344.382 us; speedup vs baseline: 1.0656x; 1.0073x over previous
//
#include <hip/hip_runtime.h>
#include <hip/hip_bf16.h>

#define H 128
#define FOURH 512
#define BATCH 64
#define SEQ 2048
#define TC SEQ

typedef _Float16 half8 __attribute__((ext_vector_type(8)));
typedef float f32x4 __attribute__((ext_vector_type(4)));

// ---- prep: fp16 hi/lo split of Wih0, summed biases, zero flags ----
__global__ void prep_kernel(const float* __restrict__ Wih0,
                            const float* __restrict__ bih0, const float* __restrict__ bhh0,
                            const float* __restrict__ bih1, const float* __restrict__ bhh1,
                            _Float16* __restrict__ w0h, _Float16* __restrict__ w0l,
                            float* __restrict__ b0, float* __restrict__ b1,
                            int* __restrict__ flags) {
    int id = blockIdx.x * 256 + threadIdx.x;
    const int NW = 512 * 256;
    if (id < NW) {
        float v = Wih0[id];
        _Float16 hi = (_Float16)v;
        w0h[id] = hi;
        w0l[id] = (_Float16)(v - (float)hi);   // exact residual, fits fp16
    } else if (id < NW + 512) {
        int i = id - NW;
        b0[i] = bih0[i] + bhh0[i];
    } else if (id < NW + 1024) {
        int i = id - (NW + 512);
        b1[i] = bih1[i] + bhh1[i];
    } else if (id < NW + 1024 + 8) {
        flags[id - (NW + 1024)] = 0;
    }
}

// ---- GEMM0 via MFMA, compensated fp16 split (error ~1e-5, fp32-grade) ----
// Fragment mapping verbatim from the R4-hardware-verified G1 worker:
//   A rows = 16 timesteps of one batch, k = (l>>4)*8+j (+kf*32), row = l&15
//   B [unit][k] row-major, col = l&15, same k
//   C col = unit (l&15), row = t0 + (l>>4)*4 + i
// acc = b0 + x_lo*W_hi + x_hi*W_lo + x_hi*W_hi  (fp32 accumulate)
// Output: R1's b-major gbuf[b][t][512].
__global__ __launch_bounds__(512) void gemm0_mfma_kernel(
    const float* __restrict__ x,        // [64][2048][256]
    const _Float16* __restrict__ w0h,   // [512][256]
    const _Float16* __restrict__ w0l,   // [512][256]
    const float* __restrict__ b0sum,    // [512]
    float* __restrict__ G)              // [64][2048][512]
{
    const int j   = blockIdx.x;         // 0..4095
    const int tc  = j >> 5;             // 0..127  (16-step chunk)
    const int sub = j & 31;
    const int by  = sub >> 2;           // batch group 0..7
    const int bx  = sub & 3;            // unit quarter 0..3
    const int n0  = bx * 128;
    const int tid = threadIdx.x;
    const int wv  = tid >> 6;           // wave -> batch within group
    const int l   = tid & 63;
    const int li  = l & 15;
    const int q   = l >> 4;             // 0..3
    const int b   = 8 * by + wv;
    const int t0  = tc * 16;

    f32x4 acc[8];
#pragma unroll
    for (int ct = 0; ct < 8; ++ct) {
        float bv = b0sum[n0 + ct * 16 + li];
        acc[ct][0] = bv; acc[ct][1] = bv; acc[ct][2] = bv; acc[ct][3] = bv;
    }

    const float* xp = x + ((size_t)b * SEQ + t0 + li) * 256 + q * 8;

    for (int kf = 0; kf < 8; ++kf) {
        float4 v0 = *(const float4*)(xp + kf * 32);
        float4 v1 = *(const float4*)(xp + kf * 32 + 4);
        half8 ah, al;
        ah[0] = (_Float16)v0.x; al[0] = (_Float16)(v0.x - (float)ah[0]);
        ah[1] = (_Float16)v0.y; al[1] = (_Float16)(v0.y - (float)ah[1]);
        ah[2] = (_Float16)v0.z; al[2] = (_Float16)(v0.z - (float)ah[2]);
        ah[3] = (_Float16)v0.w; al[3] = (_Float16)(v0.w - (float)ah[3]);
        ah[4] = (_Float16)v1.x; al[4] = (_Float16)(v1.x - (float)ah[4]);
        ah[5] = (_Float16)v1.y; al[5] = (_Float16)(v1.y - (float)ah[5]);
        ah[6] = (_Float16)v1.z; al[6] = (_Float16)(v1.z - (float)ah[6]);
        ah[7] = (_Float16)v1.w; al[7] = (_Float16)(v1.w - (float)ah[7]);
#pragma unroll
        for (int ct = 0; ct < 8; ++ct) {
            size_t woff = (size_t)(n0 + ct * 16 + li) * 256 + kf * 32 + q * 8;
            half8 bh = *(const half8*)(w0h + woff);
            half8 bl = *(const half8*)(w0l + woff);
            acc[ct] = __builtin_amdgcn_mfma_f32_16x16x32_f16(al, bh, acc[ct], 0, 0, 0);
            acc[ct] = __builtin_amdgcn_mfma_f32_16x16x32_f16(ah, bl, acc[ct], 0, 0, 0);
            acc[ct] = __builtin_amdgcn_mfma_f32_16x16x32_f16(ah, bh, acc[ct], 0, 0, 0);
        }
    }

    float* gp = G + ((size_t)b * SEQ + t0 + q * 4) * FOURH + n0 + li;
#pragma unroll
    for (int ct = 0; ct < 8; ++ct)
#pragma unroll
        for (int i = 0; i < 4; ++i)
            gp[(size_t)i * FOURH + ct * 16] = acc[ct][i];
}

// ---------------- fused 2-layer MFMA LSTM scan (R1 verbatim, 1628us proven) --
__device__ __forceinline__ float sigmoid_f(float x) {
    return __builtin_amdgcn_rcpf(1.f + __expf(-x));
}
__device__ __forceinline__ float tanh_f(float x) {
    return 1.f - 2.f * __builtin_amdgcn_rcpf(__expf(2.f * x) + 1.f);
}

// Light barrier: LDS handoff only. Global loads/stores stay in flight across it.
#define LDS_BARRIER()                                                \
    do {                                                             \
        asm volatile("s_waitcnt lgkmcnt(0)" ::: "memory");           \
        __builtin_amdgcn_s_barrier();                                \
        __builtin_amdgcn_sched_barrier(0);                           \
    } while (0)

__global__ __launch_bounds__(512, 2) void lstm_fused_kernel(
    const float* __restrict__ G,      // [64][T][512] layer-0 gate pre-activations
    const float* __restrict__ Whh0,   // [512][128]
    const float* __restrict__ Wih1,   // [512][128]
    const float* __restrict__ Whh1,   // [512][128]
    const float* __restrict__ b1,     // [512] summed layer-1 biases
    _Float16* __restrict__ h1p,       // [T][64][128] fp16 layer-0 hidden (pipe buffer)
    float* __restrict__ out,          // [64][T][128] fp32 layer-1 hidden
    int* __restrict__ flags)          // [8] progress counters (prep zeroed)
{
    const int tid = threadIdx.x;
    const int w  = tid >> 6;
    const int l  = tid & 63;
    const int li = l & 15;
    const int q  = l >> 4;
    const int u  = 16 * w + li;                 // owned hidden unit (C col)
    const int b0 = q * 2;                       // local batch for C-row r=0
    const int ab = ((li >> 2) * 2) + (li & 1);  // A-row -> local batch (dup map)

    __shared__ _Float16 hbuf[2][8][136];        // recurrent h, fp16, dbuf

    if (blockIdx.x < 8) {
        // ================= producer: layer 0 =================
        const int g = blockIdx.x;

        half8 Bf[4][4];
#pragma unroll
        for (int tl = 0; tl < 4; ++tl)
#pragma unroll
            for (int kf = 0; kf < 4; ++kf) {
                const float* wp = Whh0 + (size_t)(tl * 128 + u) * H + kf * 32 + q * 8;
                float4 v0 = *(const float4*)wp;
                float4 v1 = *(const float4*)(wp + 4);
                half8 b;
                b[0] = (_Float16)v0.x; b[1] = (_Float16)v0.y;
                b[2] = (_Float16)v0.z; b[3] = (_Float16)v0.w;
                b[4] = (_Float16)v1.x; b[5] = (_Float16)v1.y;
                b[6] = (_Float16)v1.z; b[7] = (_Float16)v1.w;
                Bf[tl][kf] = b;
            }

        float c0 = 0.f, c1 = 0.f, h0 = 0.f, h1v = 0.f;
        hbuf[0][b0][u]     = (_Float16)0.f;
        hbuf[0][b0 + 1][u] = (_Float16)0.f;

        const float* gb = G + (size_t)(8 * g) * TC * FOURH;
        const int voff0 = b0 * TC * FOURH + u;
        const int voff1 = (b0 + 1) * TC * FOURH + u;

        // depth-4 register prefetch of G (static register sets; self-reload)
        float G0[8], G1[8], G2[8], G3[8];
        const float* gld = gb;
#pragma unroll
        for (int tl = 0; tl < 4; ++tl) {
            G0[tl * 2 + 0] = gld[voff0 + tl * H];
            G0[tl * 2 + 1] = gld[voff1 + tl * H];
        }
        gld += FOURH;
#pragma unroll
        for (int tl = 0; tl < 4; ++tl) {
            G1[tl * 2 + 0] = gld[voff0 + tl * H];
            G1[tl * 2 + 1] = gld[voff1 + tl * H];
        }
        gld += FOURH;
#pragma unroll
        for (int tl = 0; tl < 4; ++tl) {
            G2[tl * 2 + 0] = gld[voff0 + tl * H];
            G2[tl * 2 + 1] = gld[voff1 + tl * H];
        }
        gld += FOURH;
#pragma unroll
        for (int tl = 0; tl < 4; ++tl) {
            G3[tl * 2 + 0] = gld[voff0 + tl * H];
            G3[tl * 2 + 1] = gld[voff1 + tl * H];
        }
        gld += FOURH;   // now points at t=4

        _Float16* php = h1p + (size_t)(8 * g + b0) * H + u;   // +step*8192
        __syncthreads();

#define P_STEP(PB, GR)                                                            \
    {                                                                             \
        half8 Afr[4];                                                             \
        _Pragma("unroll")                                                         \
        for (int kf = 0; kf < 4; ++kf)                                            \
            Afr[kf] = *(const half8*)&hbuf[PB][ab][kf * 32 + q * 8];              \
        f32x4 acc[4];                                                             \
        _Pragma("unroll")                                                         \
        for (int tl = 0; tl < 4; ++tl) {                                          \
            acc[tl][0] = GR[tl * 2 + 0]; acc[tl][1] = GR[tl * 2 + 1];             \
            acc[tl][2] = 0.f;            acc[tl][3] = 0.f;                        \
        }                                                                         \
        _Pragma("unroll")                                                         \
        for (int tl = 0; tl < 4; ++tl) {                                          \
            GR[tl * 2 + 0] = gld[voff0 + tl * H];                                 \
            GR[tl * 2 + 1] = gld[voff1 + tl * H];                                 \
        }                                                                         \
        gld += FOURH;                                                             \
        _Pragma("unroll")                                                         \
        for (int kf = 0; kf < 4; ++kf)                                            \
            _Pragma("unroll")                                                     \
            for (int tl = 0; tl < 4; ++tl)                                        \
                acc[tl] = __builtin_amdgcn_mfma_f32_16x16x32_f16(Afr[kf], Bf[tl][kf], acc[tl], 0, 0, 0); \
        {                                                                         \
            float ig = sigmoid_f(acc[0][0]);                                      \
            float fg = sigmoid_f(acc[1][0]);                                      \
            float gg = tanh_f(acc[2][0]);                                         \
            float og = sigmoid_f(acc[3][0]);                                      \
            c0 = fmaf(fg, c0, ig * gg);                                           \
            h0 = og * tanh_f(c0);                                                 \
            float ig1 = sigmoid_f(acc[0][1]);                                     \
            float fg1 = sigmoid_f(acc[1][1]);                                     \
            float gg1 = tanh_f(acc[2][1]);                                        \
            float og1 = sigmoid_f(acc[3][1]);                                     \
            c1 = fmaf(fg1, c1, ig1 * gg1);                                        \
            h1v = og1 * tanh_f(c1);                                               \
        }                                                                         \
        hbuf[PB ^ 1][b0][u]     = (_Float16)h0;                                   \
        hbuf[PB ^ 1][b0 + 1][u] = (_Float16)h1v;                                  \
        php[0]   = (_Float16)h0;                                                  \
        php[128] = (_Float16)h1v;                                                 \
        php += BATCH * H;                                                         \
        LDS_BARRIER();                                                            \
    }

        for (int s4 = 0; s4 < TC; s4 += 4) {
            P_STEP(0, G0)
            P_STEP(1, G1)
            P_STEP(0, G2)
            P_STEP(1, G3)
            if ((s4 & 15) == 12) {
                __threadfence();            // drain + make h1p stores device-visible
                __syncthreads();            // all waves fenced before flag
                if (tid == 0)
                    __hip_atomic_store(&flags[g], s4 + 4, __ATOMIC_RELEASE,
                                       __HIP_MEMORY_SCOPE_AGENT);
            }
        }
#undef P_STEP
    } else {
        // ================= consumer: layer 1 =================
        const int g = blockIdx.x - 8;

        // Bf[tl][kf]: kf<4 from Wih1 (applies to h1_t), kf>=4 from Whh1 (h2_{t-1})
        half8 Bf[4][8];
#pragma unroll
        for (int tl = 0; tl < 4; ++tl)
#pragma unroll
            for (int kf = 0; kf < 8; ++kf) {
                const float* base = (kf < 4) ? Wih1 : Whh1;
                int kk = (kf & 3) * 32 + q * 8;
                const float* wp = base + (size_t)(tl * 128 + u) * H + kk;
                float4 v0 = *(const float4*)wp;
                float4 v1 = *(const float4*)(wp + 4);
                half8 b;
                b[0] = (_Float16)v0.x; b[1] = (_Float16)v0.y;
                b[2] = (_Float16)v0.z; b[3] = (_Float16)v0.w;
                b[4] = (_Float16)v1.x; b[5] = (_Float16)v1.y;
                b[6] = (_Float16)v1.z; b[7] = (_Float16)v1.w;
                Bf[tl][kf] = b;
            }

        float bv[4];
#pragma unroll
        for (int tl = 0; tl < 4; ++tl) bv[tl] = b1[tl * 128 + u];

        float c0 = 0.f, c1 = 0.f, h0, h1v;
        hbuf[0][b0][u]     = (_Float16)0.f;
        hbuf[0][b0 + 1][u] = (_Float16)0.f;

        const _Float16* h1pG = h1p + (size_t)(8 * g + ab) * H + q * 8;  // +t*8192
        float* op0 = out + (size_t)(8 * g + b0) * SEQ * H + u;          // +step*H
        float* op1 = out + (size_t)(8 * g + b0 + 1) * SEQ * H + u;

        // initial acquire: 32-step producer lead (publishes are multiples of 16)
        if (tid == 0) {
            while (__hip_atomic_load(&flags[g], __ATOMIC_ACQUIRE,
                                     __HIP_MEMORY_SCOPE_AGENT) < 32)
                __builtin_amdgcn_s_sleep(2);
        }
        __syncthreads();

        // depth-2 register prefetch of h1 fragments (static sets, self-reload)
        half8 Af0[4], Af1[4];
#pragma unroll
        for (int kf = 0; kf < 4; ++kf)
            Af0[kf] = *(const half8*)(h1pG + kf * 32);                         // t=0
        {
            const _Float16* hp = h1pG + (size_t)(BATCH * H);                   // t=1
#pragma unroll
            for (int kf = 0; kf < 4; ++kf)
                Af1[kf] = *(const half8*)(hp + kf * 32);
        }

#define C_STEP(S, PB, AfU)                                                        \
    {                                                                             \
        half8 Ah[4];                                                              \
        _Pragma("unroll")                                                         \
        for (int kf = 0; kf < 4; ++kf)                                            \
            Ah[kf] = *(const half8*)&hbuf[PB][ab][kf * 32 + q * 8];               \
        f32x4 acc[4];                                                             \
        _Pragma("unroll")                                                         \
        for (int tl = 0; tl < 4; ++tl) {                                          \
            acc[tl][0] = bv[tl]; acc[tl][1] = bv[tl];                             \
            acc[tl][2] = bv[tl]; acc[tl][3] = bv[tl];                             \
        }                                                                         \
        _Pragma("unroll")                                                         \
        for (int kf = 0; kf < 4; ++kf)                                            \
            _Pragma("unroll")                                                     \
            for (int tl = 0; tl < 4; ++tl)                                        \
                acc[tl] = __builtin_amdgcn_mfma_f32_16x16x32_f16(AfU[kf], Bf[tl][kf], acc[tl], 0, 0, 0); \
        {                                                                         \
            int sn = (S) + 2; if (sn > TC - 1) sn = TC - 1;                       \
            const _Float16* hp = h1pG + (size_t)sn * (BATCH * H);                 \
            _Pragma("unroll")                                                     \
            for (int kf = 0; kf < 4; ++kf)                                        \
                AfU[kf] = *(const half8*)(hp + kf * 32);                          \
        }                                                                         \
        _Pragma("unroll")                                                         \
        for (int kf = 0; kf < 4; ++kf)                                            \
            _Pragma("unroll")                                                     \
            for (int tl = 0; tl < 4; ++tl)                                        \
                acc[tl] = __builtin_amdgcn_mfma_f32_16x16x32_f16(Ah[kf], Bf[tl][kf + 4], acc[tl], 0, 0, 0); \
        {                                                                         \
            float ig = sigmoid_f(acc[0][0]);                                      \
            float fg = sigmoid_f(acc[1][0]);                                      \
            float gg = tanh_f(acc[2][0]);                                         \
            float og = sigmoid_f(acc[3][0]);                                      \
            c0 = fmaf(fg, c0, ig * gg);                                           \
            h0 = og * tanh_f(c0);                                                 \
            float ig1 = sigmoid_f(acc[0][1]);                                     \
            float fg1 = sigmoid_f(acc[1][1]);                                     \
            float gg1 = tanh_f(acc[2][1]);                                        \
            float og1 = sigmoid_f(acc[3][1]);                                     \
            c1 = fmaf(fg1, c1, ig1 * gg1);                                        \
            h1v = og1 * tanh_f(c1);                                               \
        }                                                                         \
        hbuf[PB ^ 1][b0][u]     = (_Float16)h0;                                   \
        hbuf[PB ^ 1][b0 + 1][u] = (_Float16)h1v;                                  \
        op0[0] = h0;                                                              \
        op1[0] = h1v;                                                             \
        op0 += H; op1 += H;                                                       \
        LDS_BARRIER();                                                            \
    }

        for (int s4 = 0; s4 < TC; s4 += 4) {
            if (s4 && (s4 & 31) == 0) {
                if (tid == 0) {
                    int tgt = (s4 + 32 > TC) ? TC : s4 + 32;
                    while (__hip_atomic_load(&flags[g], __ATOMIC_ACQUIRE,
                                             __HIP_MEMORY_SCOPE_AGENT) < tgt)
                        __builtin_amdgcn_s_sleep(2);
                }
                __syncthreads();
            }
            C_STEP(s4 + 0, 0, Af0)
            C_STEP(s4 + 1, 1, Af1)
            C_STEP(s4 + 2, 0, Af0)
            C_STEP(s4 + 3, 1, Af1)
        }
#undef C_STEP
    }
}

// ---------------- launch ----------------
extern "C" void kernel_launch(void* const* d_in, const int* in_sizes, int n_in,
                              void* d_out, int out_size, void* d_ws, size_t ws_size,
                              hipStream_t stream) {
    const float* x    = (const float*)d_in[0];
    const float* Wih0 = (const float*)d_in[1];
    const float* Whh0 = (const float*)d_in[2];
    const float* bih0 = (const float*)d_in[3];
    const float* bhh0 = (const float*)d_in[4];
    const float* Wih1 = (const float*)d_in[5];
    const float* Whh1 = (const float*)d_in[6];
    const float* bih1 = (const float*)d_in[7];
    const float* bhh1 = (const float*)d_in[8];
    float* out = (float*)d_out;

    char* ws = (char*)d_ws;
    size_t off = 0;
    auto carve = [&](size_t bytes) -> char* {
        char* p = ws + off;
        off += (bytes + 255) & ~(size_t)255;
        return p;
    };

    _Float16*  w0h   = (_Float16*)carve(512 * 256 * 2);
    _Float16*  w0l   = (_Float16*)carve(512 * 256 * 2);
    float*     b0v   = (float*)carve(512 * 4);
    float*     b1v   = (float*)carve(512 * 4);
    _Float16*  h1p   = (_Float16*)carve((size_t)SEQ * BATCH * H * 2);
    int*       flags = (int*)carve(8 * 4);
    // +16 KB slack: producer depth-4 prefetch reads up to 4 rows past the end
    float*     gbuf  = (float*)carve((size_t)BATCH * SEQ * FOURH * 4 + 16384);

    prep_kernel<<<517, 256, 0, stream>>>(Wih0, bih0, bhh0, bih1, bhh1,
                                         w0h, w0l, b0v, b1v, flags);

    // layer-0 input GEMM via MFMA (compensated fp16 split, ~fp32 accuracy)
    gemm0_mfma_kernel<<<4096, 512, 0, stream>>>(x, w0h, w0l, b0v, gbuf);

    // fused pipelined 2-layer scan (R1 structure, 1628us proven)
    lstm_fused_kernel<<<16, 512, 0, stream>>>(gbuf, Whh0, Wih1, Whh1, b1v,
                                              h1p, out, flags);
}

// Round 11
// 2078.330 us; speedup vs baseline: 1.2020x; 1.1280x over previous
//
#include <hip/hip_runtime.h>
#include <hip/hip_bf16.h>

#define H 128
#define FOURH 512
#define BATCH 64
#define SEQ 2048
#define TC SEQ

typedef _Float16 half8 __attribute__((ext_vector_type(8)));
typedef float f32x4 __attribute__((ext_vector_type(4)));

// ---- prep: pack Wih0 into MFMA-fragment order (hi/lo fp16 split) ----
// Packed index: wp[bx][kf][ct][l][j]  (bx: col quarter, kf: K-fragment,
// ct: 16-col tile, l: lane 0..63, j: 8 halves per lane)
//   row = bx*128 + ct*16 + (l&15),  col = kf*32 + (l>>4)*8 + j
// In gemm0 a (kf,ct) weight load becomes base + lane*16B -> one contiguous
// 1KB segment per instruction (R10's was 16 scattered 64B segments).
__global__ void prep_kernel(const float* __restrict__ Wih0,
                            const float* __restrict__ bih0, const float* __restrict__ bhh0,
                            const float* __restrict__ bih1, const float* __restrict__ bhh1,
                            _Float16* __restrict__ w0h, _Float16* __restrict__ w0l,
                            float* __restrict__ b0, float* __restrict__ b1,
                            int* __restrict__ flags) {
    int id = blockIdx.x * 256 + threadIdx.x;
    const int NW = 512 * 256;
    if (id < NW) {
        int bx = id >> 15;          // 0..3
        int r  = id & 32767;
        int kf = r >> 12;           // 0..7
        int ct = (r >> 9) & 7;      // 0..7
        int l  = (r >> 3) & 63;     // lane
        int j  = r & 7;
        int li = l & 15, q = l >> 4;
        int row = bx * 128 + ct * 16 + li;
        int col = kf * 32 + q * 8 + j;
        float v = Wih0[row * 256 + col];
        _Float16 hi = (_Float16)v;
        w0h[id] = hi;
        w0l[id] = (_Float16)(v - (float)hi);   // exact residual, fits fp16
    } else if (id < NW + 512) {
        int i = id - NW;
        b0[i] = bih0[i] + bhh0[i];
    } else if (id < NW + 1024) {
        int i = id - (NW + 512);
        b1[i] = bih1[i] + bhh1[i];
    } else if (id < NW + 1024 + 8) {
        flags[id - (NW + 1024)] = 0;
    }
}

// ---- GEMM0 via MFMA, compensated fp16 split (bit-identical to R10) ----
// acc = b0 + x_lo*W_hi + x_hi*W_lo + x_hi*W_hi  (fp32 accumulate)
// Weight loads now coalesced via the packed layout; math unchanged.
__global__ __launch_bounds__(512) void gemm0_mfma_kernel(
    const float* __restrict__ x,        // [64][2048][256]
    const _Float16* __restrict__ w0h,   // packed [4][8][8][64][8]
    const _Float16* __restrict__ w0l,   // packed [4][8][8][64][8]
    const float* __restrict__ b0sum,    // [512]
    float* __restrict__ G)              // [64][2048][512]
{
    const int j   = blockIdx.x;         // 0..4095
    const int tc  = j >> 5;             // 0..127  (16-step chunk)
    const int sub = j & 31;
    const int by  = sub >> 2;           // batch group 0..7
    const int bx  = sub & 3;            // unit quarter 0..3
    const int n0  = bx * 128;
    const int tid = threadIdx.x;
    const int wv  = tid >> 6;           // wave -> batch within group
    const int l   = tid & 63;
    const int li  = l & 15;
    const int q   = l >> 4;             // 0..3
    const int b   = 8 * by + wv;
    const int t0  = tc * 16;

    f32x4 acc[8];
#pragma unroll
    for (int ct = 0; ct < 8; ++ct) {
        float bv = b0sum[n0 + ct * 16 + li];
        acc[ct][0] = bv; acc[ct][1] = bv; acc[ct][2] = bv; acc[ct][3] = bv;
    }

    const float* xp = x + ((size_t)b * SEQ + t0 + li) * 256 + q * 8;
    const int wbase0 = (bx * 8) * 4096 + l * 8;   // + kf*4096 + ct*512

    for (int kf = 0; kf < 8; ++kf) {
        float4 v0 = *(const float4*)(xp + kf * 32);
        float4 v1 = *(const float4*)(xp + kf * 32 + 4);
        half8 ah, al;
        ah[0] = (_Float16)v0.x; al[0] = (_Float16)(v0.x - (float)ah[0]);
        ah[1] = (_Float16)v0.y; al[1] = (_Float16)(v0.y - (float)ah[1]);
        ah[2] = (_Float16)v0.z; al[2] = (_Float16)(v0.z - (float)ah[2]);
        ah[3] = (_Float16)v0.w; al[3] = (_Float16)(v0.w - (float)ah[3]);
        ah[4] = (_Float16)v1.x; al[4] = (_Float16)(v1.x - (float)ah[4]);
        ah[5] = (_Float16)v1.y; al[5] = (_Float16)(v1.y - (float)ah[5]);
        ah[6] = (_Float16)v1.z; al[6] = (_Float16)(v1.z - (float)ah[6]);
        ah[7] = (_Float16)v1.w; al[7] = (_Float16)(v1.w - (float)ah[7]);
        const int wk = wbase0 + kf * 4096;
#pragma unroll
        for (int ct = 0; ct < 8; ++ct) {
            half8 bh = *(const half8*)(w0h + wk + ct * 512);
            half8 bl = *(const half8*)(w0l + wk + ct * 512);
            acc[ct] = __builtin_amdgcn_mfma_f32_16x16x32_f16(al, bh, acc[ct], 0, 0, 0);
            acc[ct] = __builtin_amdgcn_mfma_f32_16x16x32_f16(ah, bl, acc[ct], 0, 0, 0);
            acc[ct] = __builtin_amdgcn_mfma_f32_16x16x32_f16(ah, bh, acc[ct], 0, 0, 0);
        }
    }

    float* gp = G + ((size_t)b * SEQ + t0 + q * 4) * FOURH + n0 + li;
#pragma unroll
    for (int ct = 0; ct < 8; ++ct)
#pragma unroll
        for (int i = 0; i < 4; ++i)
            gp[(size_t)i * FOURH + ct * 16] = acc[ct][i];
}

// ---------------- fused 2-layer MFMA LSTM scan (R1 verbatim, 1628us proven) --
__device__ __forceinline__ float sigmoid_f(float x) {
    return __builtin_amdgcn_rcpf(1.f + __expf(-x));
}
__device__ __forceinline__ float tanh_f(float x) {
    return 1.f - 2.f * __builtin_amdgcn_rcpf(__expf(2.f * x) + 1.f);
}

// Light barrier: LDS handoff only. Global loads/stores stay in flight across it.
#define LDS_BARRIER()                                                \
    do {                                                             \
        asm volatile("s_waitcnt lgkmcnt(0)" ::: "memory");           \
        __builtin_amdgcn_s_barrier();                                \
        __builtin_amdgcn_sched_barrier(0);                           \
    } while (0)

__global__ __launch_bounds__(512, 2) void lstm_fused_kernel(
    const float* __restrict__ G,      // [64][T][512] layer-0 gate pre-activations
    const float* __restrict__ Whh0,   // [512][128]
    const float* __restrict__ Wih1,   // [512][128]
    const float* __restrict__ Whh1,   // [512][128]
    const float* __restrict__ b1,     // [512] summed layer-1 biases
    _Float16* __restrict__ h1p,       // [T][64][128] fp16 layer-0 hidden (pipe buffer)
    float* __restrict__ out,          // [64][T][128] fp32 layer-1 hidden
    int* __restrict__ flags)          // [8] progress counters (prep zeroed)
{
    const int tid = threadIdx.x;
    const int w  = tid >> 6;
    const int l  = tid & 63;
    const int li = l & 15;
    const int q  = l >> 4;
    const int u  = 16 * w + li;                 // owned hidden unit (C col)
    const int b0 = q * 2;                       // local batch for C-row r=0
    const int ab = ((li >> 2) * 2) + (li & 1);  // A-row -> local batch (dup map)

    __shared__ _Float16 hbuf[2][8][136];        // recurrent h, fp16, dbuf

    if (blockIdx.x < 8) {
        // ================= producer: layer 0 =================
        const int g = blockIdx.x;

        half8 Bf[4][4];
#pragma unroll
        for (int tl = 0; tl < 4; ++tl)
#pragma unroll
            for (int kf = 0; kf < 4; ++kf) {
                const float* wp = Whh0 + (size_t)(tl * 128 + u) * H + kf * 32 + q * 8;
                float4 v0 = *(const float4*)wp;
                float4 v1 = *(const float4*)(wp + 4);
                half8 b;
                b[0] = (_Float16)v0.x; b[1] = (_Float16)v0.y;
                b[2] = (_Float16)v0.z; b[3] = (_Float16)v0.w;
                b[4] = (_Float16)v1.x; b[5] = (_Float16)v1.y;
                b[6] = (_Float16)v1.z; b[7] = (_Float16)v1.w;
                Bf[tl][kf] = b;
            }

        float c0 = 0.f, c1 = 0.f, h0 = 0.f, h1v = 0.f;
        hbuf[0][b0][u]     = (_Float16)0.f;
        hbuf[0][b0 + 1][u] = (_Float16)0.f;

        const float* gb = G + (size_t)(8 * g) * TC * FOURH;
        const int voff0 = b0 * TC * FOURH + u;
        const int voff1 = (b0 + 1) * TC * FOURH + u;

        // depth-4 register prefetch of G (static register sets; self-reload)
        float G0[8], G1[8], G2[8], G3[8];
        const float* gld = gb;
#pragma unroll
        for (int tl = 0; tl < 4; ++tl) {
            G0[tl * 2 + 0] = gld[voff0 + tl * H];
            G0[tl * 2 + 1] = gld[voff1 + tl * H];
        }
        gld += FOURH;
#pragma unroll
        for (int tl = 0; tl < 4; ++tl) {
            G1[tl * 2 + 0] = gld[voff0 + tl * H];
            G1[tl * 2 + 1] = gld[voff1 + tl * H];
        }
        gld += FOURH;
#pragma unroll
        for (int tl = 0; tl < 4; ++tl) {
            G2[tl * 2 + 0] = gld[voff0 + tl * H];
            G2[tl * 2 + 1] = gld[voff1 + tl * H];
        }
        gld += FOURH;
#pragma unroll
        for (int tl = 0; tl < 4; ++tl) {
            G3[tl * 2 + 0] = gld[voff0 + tl * H];
            G3[tl * 2 + 1] = gld[voff1 + tl * H];
        }
        gld += FOURH;   // now points at t=4

        _Float16* php = h1p + (size_t)(8 * g + b0) * H + u;   // +step*8192
        __syncthreads();

#define P_STEP(PB, GR)                                                            \
    {                                                                             \
        half8 Afr[4];                                                             \
        _Pragma("unroll")                                                         \
        for (int kf = 0; kf < 4; ++kf)                                            \
            Afr[kf] = *(const half8*)&hbuf[PB][ab][kf * 32 + q * 8];              \
        f32x4 acc[4];                                                             \
        _Pragma("unroll")                                                         \
        for (int tl = 0; tl < 4; ++tl) {                                          \
            acc[tl][0] = GR[tl * 2 + 0]; acc[tl][1] = GR[tl * 2 + 1];             \
            acc[tl][2] = 0.f;            acc[tl][3] = 0.f;                        \
        }                                                                         \
        _Pragma("unroll")                                                         \
        for (int tl = 0; tl < 4; ++tl) {                                          \
            GR[tl * 2 + 0] = gld[voff0 + tl * H];                                 \
            GR[tl * 2 + 1] = gld[voff1 + tl * H];                                 \
        }                                                                         \
        gld += FOURH;                                                             \
        _Pragma("unroll")                                                         \
        for (int kf = 0; kf < 4; ++kf)                                            \
            _Pragma("unroll")                                                     \
            for (int tl = 0; tl < 4; ++tl)                                        \
                acc[tl] = __builtin_amdgcn_mfma_f32_16x16x32_f16(Afr[kf], Bf[tl][kf], acc[tl], 0, 0, 0); \
        {                                                                         \
            float ig = sigmoid_f(acc[0][0]);                                      \
            float fg = sigmoid_f(acc[1][0]);                                      \
            float gg = tanh_f(acc[2][0]);                                         \
            float og = sigmoid_f(acc[3][0]);                                      \
            c0 = fmaf(fg, c0, ig * gg);                                           \
            h0 = og * tanh_f(c0);                                                 \
            float ig1 = sigmoid_f(acc[0][1]);                                     \
            float fg1 = sigmoid_f(acc[1][1]);                                     \
            float gg1 = tanh_f(acc[2][1]);                                        \
            float og1 = sigmoid_f(acc[3][1]);                                     \
            c1 = fmaf(fg1, c1, ig1 * gg1);                                        \
            h1v = og1 * tanh_f(c1);                                               \
        }                                                                         \
        hbuf[PB ^ 1][b0][u]     = (_Float16)h0;                                   \
        hbuf[PB ^ 1][b0 + 1][u] = (_Float16)h1v;                                  \
        php[0]   = (_Float16)h0;                                                  \
        php[128] = (_Float16)h1v;                                                 \
        php += BATCH * H;                                                         \
        LDS_BARRIER();                                                            \
    }

        for (int s4 = 0; s4 < TC; s4 += 4) {
            P_STEP(0, G0)
            P_STEP(1, G1)
            P_STEP(0, G2)
            P_STEP(1, G3)
            if ((s4 & 15) == 12) {
                __threadfence();            // drain + make h1p stores device-visible
                __syncthreads();            // all waves fenced before flag
                if (tid == 0)
                    __hip_atomic_store(&flags[g], s4 + 4, __ATOMIC_RELEASE,
                                       __HIP_MEMORY_SCOPE_AGENT);
            }
        }
#undef P_STEP
    } else {
        // ================= consumer: layer 1 =================
        const int g = blockIdx.x - 8;

        // Bf[tl][kf]: kf<4 from Wih1 (applies to h1_t), kf>=4 from Whh1 (h2_{t-1})
        half8 Bf[4][8];
#pragma unroll
        for (int tl = 0; tl < 4; ++tl)
#pragma unroll
            for (int kf = 0; kf < 8; ++kf) {
                const float* base = (kf < 4) ? Wih1 : Whh1;
                int kk = (kf & 3) * 32 + q * 8;
                const float* wp = base + (size_t)(tl * 128 + u) * H + kk;
                float4 v0 = *(const float4*)wp;
                float4 v1 = *(const float4*)(wp + 4);
                half8 b;
                b[0] = (_Float16)v0.x; b[1] = (_Float16)v0.y;
                b[2] = (_Float16)v0.z; b[3] = (_Float16)v0.w;
                b[4] = (_Float16)v1.x; b[5] = (_Float16)v1.y;
                b[6] = (_Float16)v1.z; b[7] = (_Float16)v1.w;
                Bf[tl][kf] = b;
            }

        float bv[4];
#pragma unroll
        for (int tl = 0; tl < 4; ++tl) bv[tl] = b1[tl * 128 + u];

        float c0 = 0.f, c1 = 0.f, h0, h1v;
        hbuf[0][b0][u]     = (_Float16)0.f;
        hbuf[0][b0 + 1][u] = (_Float16)0.f;

        const _Float16* h1pG = h1p + (size_t)(8 * g + ab) * H + q * 8;  // +t*8192
        float* op0 = out + (size_t)(8 * g + b0) * SEQ * H + u;          // +step*H
        float* op1 = out + (size_t)(8 * g + b0 + 1) * SEQ * H + u;

        // initial acquire: 32-step producer lead (publishes are multiples of 16)
        if (tid == 0) {
            while (__hip_atomic_load(&flags[g], __ATOMIC_ACQUIRE,
                                     __HIP_MEMORY_SCOPE_AGENT) < 32)
                __builtin_amdgcn_s_sleep(2);
        }
        __syncthreads();

        // depth-2 register prefetch of h1 fragments (static sets, self-reload)
        half8 Af0[4], Af1[4];
#pragma unroll
        for (int kf = 0; kf < 4; ++kf)
            Af0[kf] = *(const half8*)(h1pG + kf * 32);                         // t=0
        {
            const _Float16* hp = h1pG + (size_t)(BATCH * H);                   // t=1
#pragma unroll
            for (int kf = 0; kf < 4; ++kf)
                Af1[kf] = *(const half8*)(hp + kf * 32);
        }

#define C_STEP(S, PB, AfU)                                                        \
    {                                                                             \
        half8 Ah[4];                                                              \
        _Pragma("unroll")                                                         \
        for (int kf = 0; kf < 4; ++kf)                                            \
            Ah[kf] = *(const half8*)&hbuf[PB][ab][kf * 32 + q * 8];               \
        f32x4 acc[4];                                                             \
        _Pragma("unroll")                                                         \
        for (int tl = 0; tl < 4; ++tl) {                                          \
            acc[tl][0] = bv[tl]; acc[tl][1] = bv[tl];                             \
            acc[tl][2] = bv[tl]; acc[tl][3] = bv[tl];                             \
        }                                                                         \
        _Pragma("unroll")                                                         \
        for (int kf = 0; kf < 4; ++kf)                                            \
            _Pragma("unroll")                                                     \
            for (int tl = 0; tl < 4; ++tl)                                        \
                acc[tl] = __builtin_amdgcn_mfma_f32_16x16x32_f16(AfU[kf], Bf[tl][kf], acc[tl], 0, 0, 0); \
        {                                                                         \
            int sn = (S) + 2; if (sn > TC - 1) sn = TC - 1;                       \
            const _Float16* hp = h1pG + (size_t)sn * (BATCH * H);                 \
            _Pragma("unroll")                                                     \
            for (int kf = 0; kf < 4; ++kf)                                        \
                AfU[kf] = *(const half8*)(hp + kf * 32);                          \
        }                                                                         \
        _Pragma("unroll")                                                         \
        for (int kf = 0; kf < 4; ++kf)                                            \
            _Pragma("unroll")                                                     \
            for (int tl = 0; tl < 4; ++tl)                                        \
                acc[tl] = __builtin_amdgcn_mfma_f32_16x16x32_f16(Ah[kf], Bf[tl][kf + 4], acc[tl], 0, 0, 0); \
        {                                                                         \
            float ig = sigmoid_f(acc[0][0]);                                      \
            float fg = sigmoid_f(acc[1][0]);                                      \
            float gg = tanh_f(acc[2][0]);                                         \
            float og = sigmoid_f(acc[3][0]);                                      \
            c0 = fmaf(fg, c0, ig * gg);                                           \
            h0 = og * tanh_f(c0);                                                 \
            float ig1 = sigmoid_f(acc[0][1]);                                     \
            float fg1 = sigmoid_f(acc[1][1]);                                     \
            float gg1 = tanh_f(acc[2][1]);                                        \
            float og1 = sigmoid_f(acc[3][1]);                                     \
            c1 = fmaf(fg1, c1, ig1 * gg1);                                        \
            h1v = og1 * tanh_f(c1);                                               \
        }                                                                         \
        hbuf[PB ^ 1][b0][u]     = (_Float16)h0;                                   \
        hbuf[PB ^ 1][b0 + 1][u] = (_Float16)h1v;                                  \
        op0[0] = h0;                                                              \
        op1[0] = h1v;                                                             \
        op0 += H; op1 += H;                                                       \
        LDS_BARRIER();                                                            \
    }

        for (int s4 = 0; s4 < TC; s4 += 4) {
            if (s4 && (s4 & 31) == 0) {
                if (tid == 0) {
                    int tgt = (s4 + 32 > TC) ? TC : s4 + 32;
                    while (__hip_atomic_load(&flags[g], __ATOMIC_ACQUIRE,
                                             __HIP_MEMORY_SCOPE_AGENT) < tgt)
                        __builtin_amdgcn_s_sleep(2);
                }
                __syncthreads();
            }
            C_STEP(s4 + 0, 0, Af0)
            C_STEP(s4 + 1, 1, Af1)
            C_STEP(s4 + 2, 0, Af0)
            C_STEP(s4 + 3, 1, Af1)
        }
#undef C_STEP
    }
}

// ---------------- launch ----------------
extern "C" void kernel_launch(void* const* d_in, const int* in_sizes, int n_in,
                              void* d_out, int out_size, void* d_ws, size_t ws_size,
                              hipStream_t stream) {
    const float* x    = (const float*)d_in[0];
    const float* Wih0 = (const float*)d_in[1];
    const float* Whh0 = (const float*)d_in[2];
    const float* bih0 = (const float*)d_in[3];
    const float* bhh0 = (const float*)d_in[4];
    const float* Wih1 = (const float*)d_in[5];
    const float* Whh1 = (const float*)d_in[6];
    const float* bih1 = (const float*)d_in[7];
    const float* bhh1 = (const float*)d_in[8];
    float* out = (float*)d_out;

    char* ws = (char*)d_ws;
    size_t off = 0;
    auto carve = [&](size_t bytes) -> char* {
        char* p = ws + off;
        off += (bytes + 255) & ~(size_t)255;
        return p;
    };

    _Float16*  w0h   = (_Float16*)carve(512 * 256 * 2);
    _Float16*  w0l   = (_Float16*)carve(512 * 256 * 2);
    float*     b0v   = (float*)carve(512 * 4);
    float*     b1v   = (float*)carve(512 * 4);
    _Float16*  h1p   = (_Float16*)carve((size_t)SEQ * BATCH * H * 2);
    int*       flags = (int*)carve(8 * 4);
    // +16 KB slack: producer depth-4 prefetch reads up to 4 rows past the end
    float*     gbuf  = (float*)carve((size_t)BATCH * SEQ * FOURH * 4 + 16384);

    prep_kernel<<<517, 256, 0, stream>>>(Wih0, bih0, bhh0, bih1, bhh1,
                                         w0h, w0l, b0v, b1v, flags);

    // layer-0 input GEMM via MFMA (fragment-packed weights, coalesced loads)
    gemm0_mfma_kernel<<<4096, 512, 0, stream>>>(x, w0h, w0l, b0v, gbuf);

    // fused pipelined 2-layer scan (R1 structure, 1628us proven)
    lstm_fused_kernel<<<16, 512, 0, stream>>>(gbuf, Whh0, Wih1, Whh1, b1v,
                                              h1p, out, flags);
}